// Round 4
// baseline (917.280 us; speedup 1.0000x reference)
//
#include <hip/hip_runtime.h>
#include <cstdint>
#include <cstddef>

typedef float f32x4 __attribute__((ext_vector_type(4)));
typedef short s16x8 __attribute__((ext_vector_type(8)));
typedef unsigned short u16;

static __device__ __forceinline__ u16 f2bf(float f) {
    uint32_t x = __float_as_uint(f);
    x += 0x7fffu + ((x >> 16) & 1u);   // round-to-nearest-even to bf16
    return (u16)(x >> 16);
}
static __device__ __forceinline__ float bf2f(u16 h) {
    return __uint_as_float(((uint32_t)h) << 16);
}

// Raw barrier with ONLY an LDS drain (no vmcnt!) — lets global prefetch
// loads / hseq stores stay in flight across the per-step barriers.
static __device__ __forceinline__ void bar_lds() {
    asm volatile("s_waitcnt lgkmcnt(0)" ::: "memory");
    __builtin_amdgcn_s_barrier();
    asm volatile("" ::: "memory");   // no hoisting of post-barrier reads
}

// ---------------- zero the pipeline flags (every launch; replay-safe) ------
__global__ void k_zero(int* __restrict__ p, int n) {
    int i = blockIdx.x * 256 + threadIdx.x;
    if (i < n) p[i] = 0;
}

// ---------------- split fp32 -> bf16 hi/lo ----------------
__global__ void k_split(const float* __restrict__ src, u16* __restrict__ hi,
                        u16* __restrict__ lo, int n) {
    int i = blockIdx.x * 256 + threadIdx.x;
    if (i < n) {
        float f = src[i];
        u16 h = f2bf(f);
        hi[i] = h;
        lo[i] = f2bf(f - bf2f(h));
    }
}

// ---------------- split-bf16 GEMM (layer-0 input projection) ----------------
__global__ __launch_bounds__(256, 2)
void k_gemm(const float* __restrict__ A, const u16* __restrict__ Wh,
            const u16* __restrict__ Wl, const float* __restrict__ bias,
            float* __restrict__ C, int K) {
    __shared__ __align__(16) u16 sm[32768];   // 64 KB

    const int tid  = threadIdx.x;
    const int lane = tid & 63;
    const int wave = tid >> 6;
    const int wm = wave >> 1, wn = wave & 1;

    int g = blockIdx.x;                 // 0..767
    int xcd = g & 7, ix = g >> 3;       // 96 per xcd
    int q3 = ix / 3;
    int mb = xcd + 8 * q3;              // 0..255
    int nb = ix - 3 * q3;               // 0..2
    const long m0 = (long)mb * 128;
    const int  n0 = nb * 128;

    f32x4 acc[4][4];
    const f32x4 vzero = {0.f, 0.f, 0.f, 0.f};
#pragma unroll
    for (int i = 0; i < 4; ++i)
#pragma unroll
        for (int j = 0; j < 4; ++j) acc[i][j] = vzero;

    const int ar = tid >> 1;
    const int ac = (tid & 1) * 16;
    const float* aptr = A + (m0 + ar) * (long)K + ac;
    const int br = tid >> 2;
    const int bc = (tid & 3) * 8;
    const u16* bhp = Wh + (long)(n0 + br) * K + bc;
    const u16* blp = Wl + (long)(n0 + br) * K + bc;

    const int ksteps = K >> 5;
    f32x4 a0, a1, a2, a3;

    {
        a0 = *(const f32x4*)(aptr + 0);
        a1 = *(const f32x4*)(aptr + 4);
        a2 = *(const f32x4*)(aptr + 8);
        a3 = *(const f32x4*)(aptr + 12);
#pragma unroll
        for (int c = 0; c < 2; ++c) {
            const u16* sh = bhp + (long)(c * 64) * K;
            const u16* sl = blp + (long)(c * 64) * K;
            u16* dh = &sm[8192  + c * 2048 + wave * 512];
            u16* dl = &sm[12288 + c * 2048 + wave * 512];
            __builtin_amdgcn_global_load_lds((const __attribute__((address_space(1))) void*)sh,
                                             (__attribute__((address_space(3))) void*)dh, 16, 0, 0);
            __builtin_amdgcn_global_load_lds((const __attribute__((address_space(1))) void*)sl,
                                             (__attribute__((address_space(3))) void*)dl, 16, 0, 0);
        }
        float fr[16] = {a0.x,a0.y,a0.z,a0.w, a1.x,a1.y,a1.z,a1.w,
                        a2.x,a2.y,a2.z,a2.w, a3.x,a3.y,a3.z,a3.w};
        s16x8 h0, h1, l0, l1;
#pragma unroll
        for (int i = 0; i < 8; ++i) {
            u16 hh = f2bf(fr[i]);     h0[i] = (short)hh; l0[i] = (short)f2bf(fr[i] - bf2f(hh));
            u16 hh2 = f2bf(fr[8+i]);  h1[i] = (short)hh2; l1[i] = (short)f2bf(fr[8+i] - bf2f(hh2));
        }
        u16* dh = &sm[ar * 32 + ac];
        u16* dl = &sm[4096 + ar * 32 + ac];
        *(s16x8*)dh = h0; *(s16x8*)(dh + 8) = h1;
        *(s16x8*)dl = l0; *(s16x8*)(dl + 8) = l1;
    }
    __syncthreads();

    for (int ks = 0; ks < ksteps; ++ks) {
        const int cur = ks & 1, nxt = cur ^ 1;
        const bool more = (ks + 1 < ksteps);
        if (more) {
            const int k0 = (ks + 1) << 5;
            a0 = *(const f32x4*)(aptr + k0 + 0);
            a1 = *(const f32x4*)(aptr + k0 + 4);
            a2 = *(const f32x4*)(aptr + k0 + 8);
            a3 = *(const f32x4*)(aptr + k0 + 12);
#pragma unroll
            for (int c = 0; c < 2; ++c) {
                const u16* sh = bhp + (long)(c * 64) * K + k0;
                const u16* sl = blp + (long)(c * 64) * K + k0;
                u16* dh = &sm[nxt * 16384 + 8192  + c * 2048 + wave * 512];
                u16* dl = &sm[nxt * 16384 + 12288 + c * 2048 + wave * 512];
                __builtin_amdgcn_global_load_lds((const __attribute__((address_space(1))) void*)sh,
                                                 (__attribute__((address_space(3))) void*)dh, 16, 0, 0);
                __builtin_amdgcn_global_load_lds((const __attribute__((address_space(1))) void*)sl,
                                                 (__attribute__((address_space(3))) void*)dl, 16, 0, 0);
            }
        }
        {
            const u16* base = &sm[cur * 16384];
            const int koff = (lane >> 4) * 8;
            const int rsel = lane & 15;
            s16x8 ah[4], al[4];
#pragma unroll
            for (int f = 0; f < 4; ++f) {
                int row = wm * 64 + f * 16 + rsel;
                ah[f] = *(const s16x8*)&base[row * 32 + koff];
                al[f] = *(const s16x8*)&base[4096 + row * 32 + koff];
            }
#pragma unroll
            for (int j = 0; j < 4; ++j) {
                int row = wn * 64 + j * 16 + rsel;
                s16x8 bh = *(const s16x8*)&base[8192  + row * 32 + koff];
                s16x8 bl = *(const s16x8*)&base[12288 + row * 32 + koff];
#pragma unroll
                for (int f = 0; f < 4; ++f) {
                    acc[f][j] = __builtin_amdgcn_mfma_f32_16x16x32_bf16(ah[f], bh, acc[f][j], 0, 0, 0);
                    acc[f][j] = __builtin_amdgcn_mfma_f32_16x16x32_bf16(ah[f], bl, acc[f][j], 0, 0, 0);
                    acc[f][j] = __builtin_amdgcn_mfma_f32_16x16x32_bf16(al[f], bh, acc[f][j], 0, 0, 0);
                }
            }
        }
        if (more) {
            float fr[16] = {a0.x,a0.y,a0.z,a0.w, a1.x,a1.y,a1.z,a1.w,
                            a2.x,a2.y,a2.z,a2.w, a3.x,a3.y,a3.z,a3.w};
            s16x8 h0, h1, l0, l1;
#pragma unroll
            for (int i = 0; i < 8; ++i) {
                u16 hh = f2bf(fr[i]);     h0[i] = (short)hh; l0[i] = (short)f2bf(fr[i] - bf2f(hh));
                u16 hh2 = f2bf(fr[8+i]);  h1[i] = (short)hh2; l1[i] = (short)f2bf(fr[8+i] - bf2f(hh2));
            }
            u16* dh = &sm[nxt * 16384 + ar * 32 + ac];
            u16* dl = &sm[nxt * 16384 + 4096 + ar * 32 + ac];
            *(s16x8*)dh = h0; *(s16x8*)(dh + 8) = h1;
            *(s16x8*)dl = l0; *(s16x8*)(dl + 8) = l1;
        }
        __syncthreads();
    }

    const int r0 = (lane >> 4) << 2;
    const int cn = lane & 15;
#pragma unroll
    for (int f = 0; f < 4; ++f) {
        const long mrow = m0 + wm * 64 + f * 16 + r0;
#pragma unroll
        for (int j = 0; j < 4; ++j) {
            const int n = n0 + wn * 64 + j * 16 + cn;
            const float bv = bias[n];
            float* o = C + mrow * 384 + n;
#pragma unroll
            for (int jj = 0; jj < 4; ++jj) o[(long)jj * 384] = acc[f][j][jj] + bv;
        }
    }
}

// =================== fused pipeline kernel ===================
// grid = 256 blocks x 768 threads, exactly 1 block/CU (LDS-forced).
//   blocks   0..63 : layer-0 recurrence (produce h1 + h1flag per 32-step chunk)
//   blocks  64..127: layer-1 recurrence (consume xgflag) + MLP head
//   blocks 128..255: GEMM workers: xg1 = h1 @ w_ih1^T + b_ih1 (W_ih1 in regs)

struct SmemRecur { float hsh[128]; float hp[4][384]; float xgs[2][384]; };
struct SmemGemm  { u16 ah[32*128]; u16 al[32*128]; };
union Smem {
    SmemRecur r;
    SmemGemm  g;
    char force_one_block_per_cu[81920];   // >160KiB/2 -> exactly 1 block/CU
};

__device__ __forceinline__ void recur_role(
    bool isL0, int b, const float* __restrict__ xg,
    const float* __restrict__ whh, const float* __restrict__ bhh,
    float* __restrict__ hseq, int* __restrict__ setflag, int* __restrict__ waitflag,
    const float* __restrict__ wfc1, const float* __restrict__ bfc1,
    const float* __restrict__ wfc2, const float* __restrict__ bfc2,
    float* __restrict__ out, SmemRecur& sm)
{
    const int tid = threadIdx.x;
    const int lane = tid & 63;
    const int q = tid / 192;           // wave-uniform (192 = 3 waves)
    const int u = tid - q * 192;
    const int g0 = u, g1 = u + 192;
    const int lbase = q * 8;           // wave-uniform readlane base

    float w0[32], w1r[32];
    {
        const float* p0 = whh + g0 * 128 + q * 32;
        const float* p1 = whh + g1 * 128 + q * 32;
#pragma unroll
        for (int i = 0; i < 8; ++i) {
            f32x4 a = *(const f32x4*)(p0 + 4 * i);
            w0[4*i] = a.x; w0[4*i+1] = a.y; w0[4*i+2] = a.z; w0[4*i+3] = a.w;
            f32x4 c = *(const f32x4*)(p1 + 4 * i);
            w1r[4*i] = c.x; w1r[4*i+1] = c.y; w1r[4*i+2] = c.z; w1r[4*i+3] = c.w;
        }
    }
    float bhr = 0.f, bhz = 0.f, bhn = 0.f, hreg = 0.f;
    if (tid < 128) { bhr = bhh[tid]; bhz = bhh[128 + tid]; bhn = bhh[256 + tid]; }
    if (tid < 128) sm.hsh[tid] = 0.f;

    const float* xgb = xg + (size_t)b * 512 * 384;
    __syncthreads();

    for (int t = 0; t < 512; ++t) {
        if (!isL0 && (t & 31) == 0) {
            if (tid == 0) {
                while (atomicAdd(&waitflag[b * 16 + (t >> 5)], 0) == 0)
                    __builtin_amdgcn_s_sleep(8);
                __threadfence();   // invalidate caches before reading chunk data
            }
            __syncthreads();       // full drain here is fine (16x per run)
        }
        // chunk-start (or t=0) synchronous xg row load; else prefetched last step
        if ((t == 0) || (!isL0 && (t & 31) == 0)) {
            if (tid < 384) sm.xgs[t & 1][tid] = xgb[(size_t)t * 384 + tid];
        }
        const bool pfok = (t < 511) && (isL0 || (((t + 1) & 31) != 0));
        float xnxt = 0.f;
        if (tid < 384 && pfok) xnxt = xgb[(size_t)(t + 1) * 384 + tid];

        // ---- h fetch: ONE per-lane ds_read_b128, then v_readlane extraction
        // (wave-uniform lane index) instead of 8 broadcast b128 reads/wave.
        const f32x4 hv = *(const f32x4*)(sm.hsh + ((lane & 31) << 2));

        float s0 = 0.f, s1 = 0.f;
#pragma unroll
        for (int i = 0; i < 32; ++i) {
            const float hk = __uint_as_float(
                __builtin_amdgcn_readlane(__float_as_uint(hv[i & 3]), lbase + (i >> 2)));
            s0 = fmaf(hk, w0[i], s0);
            s1 = fmaf(hk, w1r[i], s1);
        }
        sm.hp[q][g0] = s0;
        sm.hp[q][g1] = s1;
        bar_lds();         // barrier 1: partials + xgs[t] visible (LDS only!)

        if (tid < 128) {
            const int c = tid;
            float hr = sm.hp[0][c]     + sm.hp[1][c]     + sm.hp[2][c]     + sm.hp[3][c]     + bhr;
            float hz = sm.hp[0][128+c] + sm.hp[1][128+c] + sm.hp[2][128+c] + sm.hp[3][128+c] + bhz;
            float hn = sm.hp[0][256+c] + sm.hp[1][256+c] + sm.hp[2][256+c] + sm.hp[3][256+c] + bhn;
            float xr = sm.xgs[t & 1][c], xz = sm.xgs[t & 1][128 + c], xn = sm.xgs[t & 1][256 + c];
            float r = 1.f / (1.f + __expf(-(xr + hr)));
            float z = 1.f / (1.f + __expf(-(xz + hz)));
            float a = xn + r * hn;
            a = fminf(fmaxf(a, -15.f), 15.f);
            float e = __expf(2.f * a);
            float n = (e - 1.f) / (e + 1.f);
            hreg = (1.f - z) * n + z * hreg;
            sm.hsh[c] = hreg;
            if (isL0) hseq[((size_t)b * 512 + t) * 128 + c] = hreg;  // floats in flight
        }
        if (tid < 384 && pfok) sm.xgs[(t + 1) & 1][tid] = xnxt;

        const bool chunk_end = isL0 && ((t + 1) & 31) == 0;
        if (chunk_end) {
            // drain THIS thread's hseq stores before the publish barrier
            asm volatile("s_waitcnt vmcnt(0)" ::: "memory");
        }
        bar_lds();         // barrier 2: h(t) + xgs[t+1] visible (LDS only)

        if (chunk_end && tid == 0) {
            __threadfence();   // write back L2 so other XCDs can see h1 chunk
            atomicExch(&setflag[b * 16 + (t >> 5)], 1);
        }
    }

    if (!isL0 && tid < 64) {   // fused MLP head
        const float* wv = wfc1 + tid * 128;
        float acc = bfc1[tid];
#pragma unroll 8
        for (int c = 0; c < 128; ++c) acc = fmaf(sm.hsh[c], wv[c], acc);
        float p = fmaxf(acc, 0.f) * wfc2[tid];
#pragma unroll
        for (int off = 32; off > 0; off >>= 1) p += __shfl_down(p, off);
        if (tid == 0) out[b] = p + bfc2[0];
    }
}

__device__ __forceinline__ void worker_role(
    int wk, const float* __restrict__ h1, float* __restrict__ xg,
    const float* __restrict__ wih1, const float* __restrict__ bih1,
    int* __restrict__ h1flag, int* __restrict__ xgflag, SmemGemm& sm)
{
    const int tid = threadIdx.x, lane = tid & 63, w = tid >> 6;
    const int rsel = lane & 15, koff = (lane >> 4) * 8;

    // persistent W_ih1 fragments: wave w owns n-frags {2w, 2w+1}
    s16x8 bh[2][4], bl[2][4];
    float bias[2];
#pragma unroll
    for (int nfi = 0; nfi < 2; ++nfi) {
        const int n = (2 * w + nfi) * 16 + rsel;
        bias[nfi] = bih1[n];
#pragma unroll
        for (int ks = 0; ks < 4; ++ks) {
            const float* p = wih1 + n * 128 + ks * 32 + koff;
            f32x4 v0 = *(const f32x4*)p, v1 = *(const f32x4*)(p + 4);
            float fv[8] = {v0.x,v0.y,v0.z,v0.w, v1.x,v1.y,v1.z,v1.w};
            s16x8 hh, ll;
#pragma unroll
            for (int i = 0; i < 8; ++i) {
                u16 h = f2bf(fv[i]); hh[i] = (short)h; ll[i] = (short)f2bf(fv[i] - bf2f(h));
            }
            bh[nfi][ks] = hh; bl[nfi][ks] = ll;
        }
    }

    for (int j = wk; j < 1024; j += 128) {
        const int c = j >> 6, b = j & 63;
        if (tid == 0) {
            while (atomicAdd(&h1flag[b * 16 + c], 0) == 0) __builtin_amdgcn_s_sleep(8);
            __threadfence();
        }
        __syncthreads();
        // stage A = h1 rows (b, 32c..32c+31): fp32 -> split bf16 hi/lo in LDS
        if (tid < 512) {
            const int r = tid >> 4, c0 = (tid & 15) * 8;
            const float* p = h1 + ((size_t)(b * 512 + c * 32 + r)) * 128 + c0;
            f32x4 v0 = *(const f32x4*)p, v1 = *(const f32x4*)(p + 4);
            float fv[8] = {v0.x,v0.y,v0.z,v0.w, v1.x,v1.y,v1.z,v1.w};
            s16x8 hh, ll;
#pragma unroll
            for (int i = 0; i < 8; ++i) {
                u16 h = f2bf(fv[i]); hh[i] = (short)h; ll[i] = (short)f2bf(fv[i] - bf2f(h));
            }
            const int sc = c0 ^ ((r & 7) << 3);   // XOR-swizzle (T2)
            *(s16x8*)&sm.ah[r * 128 + sc] = hh;
            *(s16x8*)&sm.al[r * 128 + sc] = ll;
        }
        __syncthreads();

        f32x4 acc[2][2];
        const f32x4 vz = {0.f,0.f,0.f,0.f};
        acc[0][0] = vz; acc[0][1] = vz; acc[1][0] = vz; acc[1][1] = vz;
#pragma unroll
        for (int ks = 0; ks < 4; ++ks) {
            s16x8 a_h[2], a_l[2];
#pragma unroll
            for (int mf = 0; mf < 2; ++mf) {
                const int r = mf * 16 + rsel;
                const int si = r * 128 + ((ks * 32 + koff) ^ ((r & 7) << 3));
                a_h[mf] = *(const s16x8*)&sm.ah[si];
                a_l[mf] = *(const s16x8*)&sm.al[si];
            }
#pragma unroll
            for (int nfi = 0; nfi < 2; ++nfi)
#pragma unroll
                for (int mf = 0; mf < 2; ++mf) {
                    acc[mf][nfi] = __builtin_amdgcn_mfma_f32_16x16x32_bf16(a_h[mf], bh[nfi][ks], acc[mf][nfi], 0, 0, 0);
                    acc[mf][nfi] = __builtin_amdgcn_mfma_f32_16x16x32_bf16(a_h[mf], bl[nfi][ks], acc[mf][nfi], 0, 0, 0);
                    acc[mf][nfi] = __builtin_amdgcn_mfma_f32_16x16x32_bf16(a_l[mf], bh[nfi][ks], acc[mf][nfi], 0, 0, 0);
                }
        }
        // epilogue: xg1 rows overwrite consumed xg0 rows
#pragma unroll
        for (int mf = 0; mf < 2; ++mf)
#pragma unroll
            for (int nfi = 0; nfi < 2; ++nfi) {
                const int n = (2 * w + nfi) * 16 + rsel;
#pragma unroll
                for (int jj = 0; jj < 4; ++jj) {
                    const int m = mf * 16 + (lane >> 4) * 4 + jj;
                    xg[((size_t)(b * 512 + c * 32 + m)) * 384 + n] = acc[mf][nfi][jj] + bias[nfi];
                }
            }
        __syncthreads();   // drains stores (vmcnt0) + LDS reuse safety
        if (tid == 0) {
            __threadfence();
            atomicExch(&xgflag[b * 16 + c], 1);
        }
    }
}

__global__ __launch_bounds__(768, 3)
void k_fused(float* __restrict__ xg, float* __restrict__ h1,
             const float* __restrict__ whh0, const float* __restrict__ bhh0,
             const float* __restrict__ wih1, const float* __restrict__ bih1,
             const float* __restrict__ whh1, const float* __restrict__ bhh1,
             const float* __restrict__ wfc1, const float* __restrict__ bfc1,
             const float* __restrict__ wfc2, const float* __restrict__ bfc2,
             float* __restrict__ out, int* __restrict__ h1flag, int* __restrict__ xgflag)
{
    __shared__ __align__(16) Smem sm;
    const int bid = blockIdx.x;
    if (bid < 64) {
        recur_role(true, bid, xg, whh0, bhh0, h1, h1flag, nullptr,
                   nullptr, nullptr, nullptr, nullptr, nullptr, sm.r);
    } else if (bid < 128) {
        recur_role(false, bid - 64, xg, whh1, bhh1, nullptr, nullptr, xgflag,
                   wfc1, bfc1, wfc2, bfc2, out, sm.r);
    } else {
        worker_role(bid - 128, h1, xg, wih1, bih1, h1flag, xgflag, sm.g);
    }
}

extern "C" void kernel_launch(void* const* d_in, const int* in_sizes, int n_in,
                              void* d_out, int out_size, void* d_ws, size_t ws_size,
                              hipStream_t stream) {
    const float* x     = (const float*)d_in[0];
    const float* w_ih0 = (const float*)d_in[1];
    const float* w_hh0 = (const float*)d_in[2];
    const float* b_ih0 = (const float*)d_in[3];
    const float* b_hh0 = (const float*)d_in[4];
    const float* w_ih1 = (const float*)d_in[5];
    const float* w_hh1 = (const float*)d_in[6];
    const float* b_ih1 = (const float*)d_in[7];
    const float* b_hh1 = (const float*)d_in[8];
    const float* w_fc1 = (const float*)d_in[9];
    const float* b_fc1 = (const float*)d_in[10];
    const float* w_fc2 = (const float*)d_in[11];
    const float* b_fc2 = (const float*)d_in[12];
    float* out = (float*)d_out;
    (void)in_sizes; (void)n_in; (void)out_size; (void)ws_size;

    char* ws = (char*)d_ws;
    float* xg    = (float*)(ws + 0);          // 32768*384*4 = 50331648 (xg0, then xg1 in place)
    float* h1    = (float*)(ws + 50331648);   // 32768*128*4 = 16777216
    u16*   w0h   = (u16*)(ws + 67108864);     // 786432*2 = 1572864
    u16*   w0l   = (u16*)(ws + 68681728);     // 1572864
    int*   h1flag = (int*)(ws + 70254592);    // 1024 ints
    int*   xgflag = h1flag + 1024;            // 1024 ints; end ~70.3 MB

    k_zero<<<8, 256, 0, stream>>>(h1flag, 2048);
    k_split<<<3072, 256, 0, stream>>>(w_ih0, w0h, w0l, 384 * 2048);
    k_gemm<<<768, 256, 0, stream>>>(x, w0h, w0l, b_ih0, xg, 2048);
    k_fused<<<256, 768, 0, stream>>>(xg, h1, w_hh0, b_hh0, w_ih1, b_ih1,
                                     w_hh1, b_hh1, w_fc1, b_fc1, w_fc2, b_fc2,
                                     out, h1flag, xgflag);
}

// Round 5
// 621.926 us; speedup vs baseline: 1.4749x; 1.4749x over previous
//
#include <hip/hip_runtime.h>
#include <cstdint>
#include <cstddef>

typedef float f32x4 __attribute__((ext_vector_type(4)));
typedef float f32x2 __attribute__((ext_vector_type(2)));
typedef short s16x8 __attribute__((ext_vector_type(8)));
typedef unsigned short u16;

static __device__ __forceinline__ u16 f2bf(float f) {
    uint32_t x = __float_as_uint(f);
    x += 0x7fffu + ((x >> 16) & 1u);   // round-to-nearest-even to bf16
    return (u16)(x >> 16);
}
static __device__ __forceinline__ float bf2f(u16 h) {
    return __uint_as_float(((uint32_t)h) << 16);
}

// Raw barrier with ONLY an LDS drain (no vmcnt) — prefetch loads / hseq
// stores stay in flight across the per-step barriers.
static __device__ __forceinline__ void bar_lds() {
    asm volatile("s_waitcnt lgkmcnt(0)" ::: "memory");
    __builtin_amdgcn_s_barrier();
    asm volatile("" ::: "memory");
}

// ---------------- zero the pipeline flags (every launch; replay-safe) ------
__global__ void k_zero(int* __restrict__ p, int n) {
    int i = blockIdx.x * 256 + threadIdx.x;
    if (i < n) p[i] = 0;
}

// ---------------- split fp32 -> bf16 hi/lo ----------------
__global__ void k_split(const float* __restrict__ src, u16* __restrict__ hi,
                        u16* __restrict__ lo, int n) {
    int i = blockIdx.x * 256 + threadIdx.x;
    if (i < n) {
        float f = src[i];
        u16 h = f2bf(f);
        hi[i] = h;
        lo[i] = f2bf(f - bf2f(h));
    }
}

// ---------------- split-bf16 GEMM (layer-0 input projection) ----------------
__global__ __launch_bounds__(256, 2)
void k_gemm(const float* __restrict__ A, const u16* __restrict__ Wh,
            const u16* __restrict__ Wl, const float* __restrict__ bias,
            float* __restrict__ C, int K) {
    __shared__ __align__(16) u16 sm[32768];   // 64 KB

    const int tid  = threadIdx.x;
    const int lane = tid & 63;
    const int wave = tid >> 6;
    const int wm = wave >> 1, wn = wave & 1;

    int g = blockIdx.x;                 // 0..767
    int xcd = g & 7, ix = g >> 3;       // 96 per xcd
    int q3 = ix / 3;
    int mb = xcd + 8 * q3;              // 0..255
    int nb = ix - 3 * q3;               // 0..2
    const long m0 = (long)mb * 128;
    const int  n0 = nb * 128;

    f32x4 acc[4][4];
    const f32x4 vzero = {0.f, 0.f, 0.f, 0.f};
#pragma unroll
    for (int i = 0; i < 4; ++i)
#pragma unroll
        for (int j = 0; j < 4; ++j) acc[i][j] = vzero;

    const int ar = tid >> 1;
    const int ac = (tid & 1) * 16;
    const float* aptr = A + (m0 + ar) * (long)K + ac;
    const int br = tid >> 2;
    const int bc = (tid & 3) * 8;
    const u16* bhp = Wh + (long)(n0 + br) * K + bc;
    const u16* blp = Wl + (long)(n0 + br) * K + bc;

    const int ksteps = K >> 5;
    f32x4 a0, a1, a2, a3;

    {
        a0 = *(const f32x4*)(aptr + 0);
        a1 = *(const f32x4*)(aptr + 4);
        a2 = *(const f32x4*)(aptr + 8);
        a3 = *(const f32x4*)(aptr + 12);
#pragma unroll
        for (int c = 0; c < 2; ++c) {
            const u16* sh = bhp + (long)(c * 64) * K;
            const u16* sl = blp + (long)(c * 64) * K;
            u16* dh = &sm[8192  + c * 2048 + wave * 512];
            u16* dl = &sm[12288 + c * 2048 + wave * 512];
            __builtin_amdgcn_global_load_lds((const __attribute__((address_space(1))) void*)sh,
                                             (__attribute__((address_space(3))) void*)dh, 16, 0, 0);
            __builtin_amdgcn_global_load_lds((const __attribute__((address_space(1))) void*)sl,
                                             (__attribute__((address_space(3))) void*)dl, 16, 0, 0);
        }
        float fr[16] = {a0.x,a0.y,a0.z,a0.w, a1.x,a1.y,a1.z,a1.w,
                        a2.x,a2.y,a2.z,a2.w, a3.x,a3.y,a3.z,a3.w};
        s16x8 h0, h1, l0, l1;
#pragma unroll
        for (int i = 0; i < 8; ++i) {
            u16 hh = f2bf(fr[i]);     h0[i] = (short)hh; l0[i] = (short)f2bf(fr[i] - bf2f(hh));
            u16 hh2 = f2bf(fr[8+i]);  h1[i] = (short)hh2; l1[i] = (short)f2bf(fr[8+i] - bf2f(hh2));
        }
        u16* dh = &sm[ar * 32 + ac];
        u16* dl = &sm[4096 + ar * 32 + ac];
        *(s16x8*)dh = h0; *(s16x8*)(dh + 8) = h1;
        *(s16x8*)dl = l0; *(s16x8*)(dl + 8) = l1;
    }
    __syncthreads();

    for (int ks = 0; ks < ksteps; ++ks) {
        const int cur = ks & 1, nxt = cur ^ 1;
        const bool more = (ks + 1 < ksteps);
        if (more) {
            const int k0 = (ks + 1) << 5;
            a0 = *(const f32x4*)(aptr + k0 + 0);
            a1 = *(const f32x4*)(aptr + k0 + 4);
            a2 = *(const f32x4*)(aptr + k0 + 8);
            a3 = *(const f32x4*)(aptr + k0 + 12);
#pragma unroll
            for (int c = 0; c < 2; ++c) {
                const u16* sh = bhp + (long)(c * 64) * K + k0;
                const u16* sl = blp + (long)(c * 64) * K + k0;
                u16* dh = &sm[nxt * 16384 + 8192  + c * 2048 + wave * 512];
                u16* dl = &sm[nxt * 16384 + 12288 + c * 2048 + wave * 512];
                __builtin_amdgcn_global_load_lds((const __attribute__((address_space(1))) void*)sh,
                                                 (__attribute__((address_space(3))) void*)dh, 16, 0, 0);
                __builtin_amdgcn_global_load_lds((const __attribute__((address_space(1))) void*)sl,
                                                 (__attribute__((address_space(3))) void*)dl, 16, 0, 0);
            }
        }
        {
            const u16* base = &sm[cur * 16384];
            const int koff = (lane >> 4) * 8;
            const int rsel = lane & 15;
            s16x8 ah[4], al[4];
#pragma unroll
            for (int f = 0; f < 4; ++f) {
                int row = wm * 64 + f * 16 + rsel;
                ah[f] = *(const s16x8*)&base[row * 32 + koff];
                al[f] = *(const s16x8*)&base[4096 + row * 32 + koff];
            }
#pragma unroll
            for (int j = 0; j < 4; ++j) {
                int row = wn * 64 + j * 16 + rsel;
                s16x8 bh = *(const s16x8*)&base[8192  + row * 32 + koff];
                s16x8 bl = *(const s16x8*)&base[12288 + row * 32 + koff];
#pragma unroll
                for (int f = 0; f < 4; ++f) {
                    acc[f][j] = __builtin_amdgcn_mfma_f32_16x16x32_bf16(ah[f], bh, acc[f][j], 0, 0, 0);
                    acc[f][j] = __builtin_amdgcn_mfma_f32_16x16x32_bf16(ah[f], bl, acc[f][j], 0, 0, 0);
                    acc[f][j] = __builtin_amdgcn_mfma_f32_16x16x32_bf16(al[f], bh, acc[f][j], 0, 0, 0);
                }
            }
        }
        if (more) {
            float fr[16] = {a0.x,a0.y,a0.z,a0.w, a1.x,a1.y,a1.z,a1.w,
                            a2.x,a2.y,a2.z,a2.w, a3.x,a3.y,a3.z,a3.w};
            s16x8 h0, h1, l0, l1;
#pragma unroll
            for (int i = 0; i < 8; ++i) {
                u16 hh = f2bf(fr[i]);     h0[i] = (short)hh; l0[i] = (short)f2bf(fr[i] - bf2f(hh));
                u16 hh2 = f2bf(fr[8+i]);  h1[i] = (short)hh2; l1[i] = (short)f2bf(fr[8+i] - bf2f(hh2));
            }
            u16* dh = &sm[nxt * 16384 + ar * 32 + ac];
            u16* dl = &sm[nxt * 16384 + 4096 + ar * 32 + ac];
            *(s16x8*)dh = h0; *(s16x8*)(dh + 8) = h1;
            *(s16x8*)dl = l0; *(s16x8*)(dl + 8) = l1;
        }
        __syncthreads();
    }

    const int r0 = (lane >> 4) << 2;
    const int cn = lane & 15;
#pragma unroll
    for (int f = 0; f < 4; ++f) {
        const long mrow = m0 + wm * 64 + f * 16 + r0;
#pragma unroll
        for (int j = 0; j < 4; ++j) {
            const int n = n0 + wn * 64 + j * 16 + cn;
            const float bv = bias[n];
            float* o = C + mrow * 384 + n;
#pragma unroll
            for (int jj = 0; jj < 4; ++jj) o[(long)jj * 384] = acc[f][j][jj] + bv;
        }
    }
}

// =================== fused pipeline kernel ===================
// grid = 256 blocks x 512 threads, 1 block/CU (LDS-forced).
//   blocks   0..63 : layer-0 recurrence (produce h1 + flag per 16-step chunk)
//   blocks  64..127: layer-1 recurrence (consume xgflag) + MLP head
//   blocks 128..255: GEMM workers: xg1 = h1 @ w_ih1^T + b_ih1 (W_ih1 in regs)
//
// Recurrence (8 waves): wave w owns k-slice [16w,16w+16); lane owns gates
// 6*lane..6*lane+5 => 4 LDS broadcast b128 + 96 FMA + 3 b64 partial writes
// per wave per step (LDS bytes/step: 98KB -> ~33KB vs r3).  Epilogue on
// tid<128 with direct-register 4-deep double-buffered xg prefetch.

struct SmemRecur { float hsh[128]; float hp[8][384]; };
struct SmemGemm  { u16 ah[16 * 128]; u16 al[16 * 128]; };
union Smem {
    SmemRecur r;
    SmemGemm  g;
    char force_one_block_per_cu[98304];   // 96KB: strictly 1 block/CU
};

#define R_ISSUE(BUF, G) do {                                                  \
    const int _G = (G);                                                       \
    if (_G < 128 && tid < 128) {                                              \
        if (!isL0 && (_G & 3) == 0) {                                         \
            if ((tid & 63) == 0) {                                            \
                while (atomicAdd(&waitflag[b * 32 + (_G >> 2)], 0) == 0)      \
                    __builtin_amdgcn_s_sleep(8);                              \
            }                                                                 \
            __threadfence();                                                  \
        }                                                                     \
        const float* _p = xgb + (size_t)(4 * _G) * 384 + tid;                 \
        BUF[0] = _p[0];    BUF[1] = _p[128];   BUF[2]  = _p[256];             \
        BUF[3] = _p[384];  BUF[4] = _p[512];   BUF[5]  = _p[640];             \
        BUF[6] = _p[768];  BUF[7] = _p[896];   BUF[8]  = _p[1024];            \
        BUF[9] = _p[1152]; BUF[10] = _p[1280]; BUF[11] = _p[1408];            \
    } } while (0)

#define R_STEP(T, BUF, J) do {                                                \
    const int _t = (T);                                                       \
    f32x4 _h0 = *(const f32x4*)(sm.hsh + 16 * w + 0);                         \
    f32x4 _h1 = *(const f32x4*)(sm.hsh + 16 * w + 4);                         \
    f32x4 _h2 = *(const f32x4*)(sm.hsh + 16 * w + 8);                         \
    f32x4 _h3 = *(const f32x4*)(sm.hsh + 16 * w + 12);                        \
    float _ha[16];                                                            \
    _ha[0]=_h0[0];  _ha[1]=_h0[1];  _ha[2]=_h0[2];  _ha[3]=_h0[3];            \
    _ha[4]=_h1[0];  _ha[5]=_h1[1];  _ha[6]=_h1[2];  _ha[7]=_h1[3];            \
    _ha[8]=_h2[0];  _ha[9]=_h2[1];  _ha[10]=_h2[2]; _ha[11]=_h2[3];           \
    _ha[12]=_h3[0]; _ha[13]=_h3[1]; _ha[14]=_h3[2]; _ha[15]=_h3[3];           \
    float _s0=0.f,_s1=0.f,_s2=0.f,_s3=0.f,_s4=0.f,_s5=0.f;                    \
    _Pragma("unroll")                                                         \
    for (int _i = 0; _i < 16; ++_i) {                                         \
        const float _hv = _ha[_i];                                            \
        _s0 = fmaf(_hv, wr[0][_i], _s0); _s1 = fmaf(_hv, wr[1][_i], _s1);     \
        _s2 = fmaf(_hv, wr[2][_i], _s2); _s3 = fmaf(_hv, wr[3][_i], _s3);     \
        _s4 = fmaf(_hv, wr[4][_i], _s4); _s5 = fmaf(_hv, wr[5][_i], _s5);     \
    }                                                                         \
    *(f32x2*)&sm.hp[w][g6 + 0] = (f32x2){_s0, _s1};                           \
    *(f32x2*)&sm.hp[w][g6 + 2] = (f32x2){_s2, _s3};                           \
    *(f32x2*)&sm.hp[w][g6 + 4] = (f32x2){_s4, _s5};                           \
    const bool _pub = isL0 && _t > 0 && (_t & 15) == 0;                       \
    if (_pub && tid < 128) asm volatile("s_waitcnt vmcnt(12)" ::: "memory");  \
    bar_lds();                                                                \
    if (_pub && tid == 0) {                                                   \
        __threadfence();                                                      \
        atomicExch(&setflag[b * 32 + ((_t >> 4) - 1)], 1);                    \
    }                                                                         \
    if (tid < 128) {                                                          \
        const int _c = tid;                                                   \
        float _hr = bhr, _hz = bhz, _hn = bhn;                                \
        _Pragma("unroll")                                                     \
        for (int _q = 0; _q < 8; ++_q) {                                      \
            _hr += sm.hp[_q][_c];                                             \
            _hz += sm.hp[_q][128 + _c];                                       \
            _hn += sm.hp[_q][256 + _c];                                       \
        }                                                                     \
        const float _xr = BUF[(J) * 3 + 0];                                   \
        const float _xz = BUF[(J) * 3 + 1];                                   \
        const float _xn = BUF[(J) * 3 + 2];                                   \
        const float _r = 1.f / (1.f + __expf(-(_xr + _hr)));                  \
        const float _z = 1.f / (1.f + __expf(-(_xz + _hz)));                  \
        float _a = _xn + _r * _hn;                                            \
        _a = fminf(fmaxf(_a, -15.f), 15.f);                                   \
        const float _e = __expf(2.f * _a);                                    \
        const float _n = (_e - 1.f) / (_e + 1.f);                             \
        hreg = (1.f - _z) * _n + _z * hreg;                                   \
        sm.hsh[_c] = hreg;                                                    \
        if (isL0) hseq[((size_t)(b * 512 + _t)) * 128 + _c] = hreg;           \
    }                                                                         \
    bar_lds();                                                                \
} while (0)

__device__ __forceinline__ void recur_role(
    bool isL0, int b, const float* __restrict__ xg,
    const float* __restrict__ whh, const float* __restrict__ bhh,
    float* __restrict__ hseq, int* __restrict__ setflag, int* __restrict__ waitflag,
    const float* __restrict__ wfc1, const float* __restrict__ bfc1,
    const float* __restrict__ wfc2, const float* __restrict__ bfc2,
    float* __restrict__ out, SmemRecur& sm)
{
    const int tid  = threadIdx.x;       // 0..511
    const int w    = tid >> 6;          // k-slice 0..7 (wave-uniform)
    const int lane = tid & 63;
    const int g6   = 6 * lane;          // first of this lane's 6 gates

    // per-lane weights: wr[j][i] = whh[(g6+j)*128 + 16w + i]
    float wr[6][16];
#pragma unroll
    for (int j = 0; j < 6; ++j) {
        const float* p = whh + (size_t)(g6 + j) * 128 + 16 * w;
#pragma unroll
        for (int i4 = 0; i4 < 4; ++i4) {
            f32x4 v = *(const f32x4*)(p + 4 * i4);
            wr[j][4*i4+0] = v[0]; wr[j][4*i4+1] = v[1];
            wr[j][4*i4+2] = v[2]; wr[j][4*i4+3] = v[3];
        }
    }
    float bhr = 0.f, bhz = 0.f, bhn = 0.f, hreg = 0.f;
    if (tid < 128) {
        bhr = bhh[tid]; bhz = bhh[128 + tid]; bhn = bhh[256 + tid];
        sm.hsh[tid] = 0.f;
    }
    const float* xgb = xg + (size_t)b * 512 * 384;

    float pA[12], pB[12];
    R_ISSUE(pA, 0);
    R_ISSUE(pB, 1);
    __syncthreads();   // hsh init visible

    for (int gp = 0; gp < 64; ++gp) {
        const int t0 = gp * 8;
        R_STEP(t0 + 0, pA, 0); R_STEP(t0 + 1, pA, 1);
        R_STEP(t0 + 2, pA, 2); R_STEP(t0 + 3, pA, 3);
        R_ISSUE(pA, 2 * gp + 2);
        R_STEP(t0 + 4, pB, 0); R_STEP(t0 + 5, pB, 1);
        R_STEP(t0 + 6, pB, 2); R_STEP(t0 + 7, pB, 3);
        R_ISSUE(pB, 2 * gp + 3);
    }

    if (isL0) {   // final chunk publish
        if (tid < 128) asm volatile("s_waitcnt vmcnt(0)" ::: "memory");
        __syncthreads();
        if (tid == 0) { __threadfence(); atomicExch(&setflag[b * 32 + 31], 1); }
    }

    if (!isL0 && tid < 64) {   // fused MLP head
        const float* wv = wfc1 + tid * 128;
        float acc = bfc1[tid];
#pragma unroll 8
        for (int c = 0; c < 128; ++c) acc = fmaf(sm.hsh[c], wv[c], acc);
        float p = fmaxf(acc, 0.f) * wfc2[tid];
#pragma unroll
        for (int off = 32; off > 0; off >>= 1) p += __shfl_down(p, off);
        if (tid == 0) out[b] = p + bfc2[0];
    }
}

__device__ __forceinline__ void worker_role(
    int wk, const float* __restrict__ h1, float* __restrict__ xg,
    const float* __restrict__ wih1, const float* __restrict__ bih1,
    int* __restrict__ h1flag, int* __restrict__ xgflag, SmemGemm& sm)
{
    const int tid = threadIdx.x, lane = tid & 63, w = tid >> 6;   // 8 waves
    const int rsel = lane & 15, koff = (lane >> 4) * 8;

    // persistent W_ih1 fragments: wave w owns n-frags {3w, 3w+1, 3w+2}
    s16x8 bh[3][4], bl[3][4];
    float bias[3];
#pragma unroll
    for (int nfi = 0; nfi < 3; ++nfi) {
        const int n = (3 * w + nfi) * 16 + rsel;
        bias[nfi] = bih1[n];
#pragma unroll
        for (int ks = 0; ks < 4; ++ks) {
            const float* p = wih1 + n * 128 + ks * 32 + koff;
            f32x4 v0 = *(const f32x4*)p, v1 = *(const f32x4*)(p + 4);
            float fv[8] = {v0[0],v0[1],v0[2],v0[3], v1[0],v1[1],v1[2],v1[3]};
            s16x8 hh, ll;
#pragma unroll
            for (int i = 0; i < 8; ++i) {
                u16 h = f2bf(fv[i]); hh[i] = (short)h; ll[i] = (short)f2bf(fv[i] - bf2f(h));
            }
            bh[nfi][ks] = hh; bl[nfi][ks] = ll;
        }
    }

    for (int j = wk; j < 2048; j += 128) {
        const int c = j >> 6, b = j & 63;     // c: 16-step chunk index 0..31
        if (tid == 0) {
            while (atomicAdd(&h1flag[b * 32 + c], 0) == 0) __builtin_amdgcn_s_sleep(8);
            __threadfence();
        }
        __syncthreads();
        // stage A = h1 rows (b, 16c..16c+15): fp32 -> split bf16 hi/lo in LDS
        if (tid < 256) {
            const int r = tid >> 4, c0 = (tid & 15) * 8;
            const float* p = h1 + ((size_t)(b * 512 + c * 16 + r)) * 128 + c0;
            f32x4 v0 = *(const f32x4*)p, v1 = *(const f32x4*)(p + 4);
            float fv[8] = {v0[0],v0[1],v0[2],v0[3], v1[0],v1[1],v1[2],v1[3]};
            s16x8 hh, ll;
#pragma unroll
            for (int i = 0; i < 8; ++i) {
                u16 h = f2bf(fv[i]); hh[i] = (short)h; ll[i] = (short)f2bf(fv[i] - bf2f(h));
            }
            const int sc = c0 ^ ((r & 7) << 3);   // XOR-swizzle (T2)
            *(s16x8*)&sm.ah[r * 128 + sc] = hh;
            *(s16x8*)&sm.al[r * 128 + sc] = ll;
        }
        __syncthreads();

        f32x4 acc[3];
        const f32x4 vz = {0.f, 0.f, 0.f, 0.f};
        acc[0] = vz; acc[1] = vz; acc[2] = vz;
#pragma unroll
        for (int ks = 0; ks < 4; ++ks) {
            const int si = rsel * 128 + ((ks * 32 + koff) ^ ((rsel & 7) << 3));
            s16x8 a_h = *(const s16x8*)&sm.ah[si];
            s16x8 a_l = *(const s16x8*)&sm.al[si];
#pragma unroll
            for (int nfi = 0; nfi < 3; ++nfi) {
                acc[nfi] = __builtin_amdgcn_mfma_f32_16x16x32_bf16(a_h, bh[nfi][ks], acc[nfi], 0, 0, 0);
                acc[nfi] = __builtin_amdgcn_mfma_f32_16x16x32_bf16(a_h, bl[nfi][ks], acc[nfi], 0, 0, 0);
                acc[nfi] = __builtin_amdgcn_mfma_f32_16x16x32_bf16(a_l, bh[nfi][ks], acc[nfi], 0, 0, 0);
            }
        }
        // epilogue: xg1 rows overwrite consumed xg0 rows
#pragma unroll
        for (int nfi = 0; nfi < 3; ++nfi) {
            const int n = (3 * w + nfi) * 16 + rsel;
#pragma unroll
            for (int jj = 0; jj < 4; ++jj) {
                const int m = (lane >> 4) * 4 + jj;
                xg[((size_t)(b * 512 + c * 16 + m)) * 384 + n] = acc[nfi][jj] + bias[nfi];
            }
        }
        __syncthreads();   // drains stores (vmcnt0) + LDS reuse safety
        if (tid == 0) {
            __threadfence();
            atomicExch(&xgflag[b * 32 + c], 1);
        }
    }
}

__global__ __launch_bounds__(512, 2)
void k_fused(float* __restrict__ xg, float* __restrict__ h1,
             const float* __restrict__ whh0, const float* __restrict__ bhh0,
             const float* __restrict__ wih1, const float* __restrict__ bih1,
             const float* __restrict__ whh1, const float* __restrict__ bhh1,
             const float* __restrict__ wfc1, const float* __restrict__ bfc1,
             const float* __restrict__ wfc2, const float* __restrict__ bfc2,
             float* __restrict__ out, int* __restrict__ h1flag, int* __restrict__ xgflag)
{
    __shared__ __align__(16) Smem sm;
    const int bid = blockIdx.x;
    if (bid < 64) {
        recur_role(true, bid, xg, whh0, bhh0, h1, h1flag, nullptr,
                   nullptr, nullptr, nullptr, nullptr, nullptr, sm.r);
    } else if (bid < 128) {
        recur_role(false, bid - 64, xg, whh1, bhh1, nullptr, nullptr, xgflag,
                   wfc1, bfc1, wfc2, bfc2, out, sm.r);
    } else {
        worker_role(bid - 128, h1, xg, wih1, bih1, h1flag, xgflag, sm.g);
    }
}

extern "C" void kernel_launch(void* const* d_in, const int* in_sizes, int n_in,
                              void* d_out, int out_size, void* d_ws, size_t ws_size,
                              hipStream_t stream) {
    const float* x     = (const float*)d_in[0];
    const float* w_ih0 = (const float*)d_in[1];
    const float* w_hh0 = (const float*)d_in[2];
    const float* b_ih0 = (const float*)d_in[3];
    const float* b_hh0 = (const float*)d_in[4];
    const float* w_ih1 = (const float*)d_in[5];
    const float* w_hh1 = (const float*)d_in[6];
    const float* b_ih1 = (const float*)d_in[7];
    const float* b_hh1 = (const float*)d_in[8];
    const float* w_fc1 = (const float*)d_in[9];
    const float* b_fc1 = (const float*)d_in[10];
    const float* w_fc2 = (const float*)d_in[11];
    const float* b_fc2 = (const float*)d_in[12];
    float* out = (float*)d_out;
    (void)in_sizes; (void)n_in; (void)out_size; (void)ws_size;

    char* ws = (char*)d_ws;
    float* xg     = (float*)(ws + 0);          // 32768*384*4 (xg0, then xg1 in place)
    float* h1     = (float*)(ws + 50331648);   // 32768*128*4
    u16*   w0h    = (u16*)(ws + 67108864);     // 786432*2
    u16*   w0l    = (u16*)(ws + 68681728);     // 786432*2
    int*   h1flag = (int*)(ws + 70254592);     // 2048 ints
    int*   xgflag = h1flag + 2048;             // 2048 ints

    k_zero<<<16, 256, 0, stream>>>(h1flag, 4096);
    k_split<<<3072, 256, 0, stream>>>(w_ih0, w0h, w0l, 384 * 2048);
    k_gemm<<<768, 256, 0, stream>>>(x, w0h, w0l, b_ih0, xg, 2048);
    k_fused<<<256, 512, 0, stream>>>(xg, h1, w_hh0, b_hh0, w_ih1, b_ih1,
                                     w_hh1, b_hh1, w_fc1, b_fc1, w_fc2, b_fc2,
                                     out, h1flag, xgflag);
}